// Round 5
// baseline (451.720 us; speedup 1.0000x reference)
//
#include <hip/hip_runtime.h>

#define N_NODES 20000
#define N_EDGES 320000
#define N_FEAT 128
#define MLP_HID 64
#define N_GRAPHS 16
#define N_LAYERS 5
#define EPS 1e-5f

typedef __attribute__((ext_vector_type(8))) short short8;   // 8 bf16 = 4 VGPRs (MFMA A/B frag)
typedef __attribute__((ext_vector_type(4))) float f32x4;    // MFMA C/D frag

__device__ inline float bf2f(unsigned short u) { return __uint_as_float(((unsigned)u) << 16); }
__device__ inline unsigned short f2bf(float f) {
  unsigned u = __float_as_uint(f);
  u += 0x7FFF + ((u >> 16) & 1);  // RNE
  return (unsigned short)(u >> 16);
}

// ---------------- CSR build ----------------

__global__ __launch_bounds__(256) void k_deg(const int* __restrict__ dst, int* __restrict__ deg) {
  int e = blockIdx.x * 256 + threadIdx.x;  // grid exact: 1250*256 = 320000
  atomicAdd(&deg[dst[e]], 1);
}

__global__ __launch_bounds__(1024) void k_scan(const int* __restrict__ deg, int* __restrict__ rowptr,
                                               int* __restrict__ cursor, const int* __restrict__ batch,
                                               float* __restrict__ cntf, float* __restrict__ zero_region) {
  __shared__ int sdata[1024];
  __shared__ int spos[17];
  constexpr int CH = 20;  // 1024*20 = 20480 >= 20000
  int t = threadIdx.x;
  // zero all per-layer stat buffers + pooled (contiguous: 22528 floats)
  for (int i = t; i < 22528; i += 1024) zero_region[i] = 0.0f;
  int base = t * CH;
  int loc[CH];
  int partial = 0;
#pragma unroll
  for (int i = 0; i < CH; i++) {
    int idx = base + i;
    int v = (idx < N_NODES) ? deg[idx] : 0;
    loc[i] = v;
    partial += v;
  }
  sdata[t] = partial;
  __syncthreads();
  for (int off = 1; off < 1024; off <<= 1) {
    int v = (t >= off) ? sdata[t - off] : 0;
    __syncthreads();
    sdata[t] += v;
    __syncthreads();
  }
  int run = sdata[t] - partial;  // exclusive prefix
#pragma unroll
  for (int i = 0; i < CH; i++) {
    int idx = base + i;
    if (idx < N_NODES) {
      rowptr[idx] = run;
      cursor[idx] = run;
      run += loc[i];
    }
  }
  if (t == 1023) rowptr[N_NODES] = sdata[1023];
  if (t < 17) {  // per-graph counts via binary search on sorted batch
    int lo = 0, hi = N_NODES;
    while (lo < hi) {
      int mid = (lo + hi) >> 1;
      if (batch[mid] < t) lo = mid + 1; else hi = mid;
    }
    spos[t] = lo;
  }
  __syncthreads();
  if (t < N_GRAPHS) cntf[t] = fmaxf((float)(spos[t + 1] - spos[t]), 1.0f);
}

__global__ __launch_bounds__(256) void k_fill(const int* __restrict__ src, const int* __restrict__ dst,
                                              int* __restrict__ cursor, int* __restrict__ src_sorted) {
  int e = blockIdx.x * 256 + threadIdx.x;  // grid exact
  int d = dst[e];
  int p = atomicAdd(&cursor[d], 1);
  src_sorted[p] = src[e];
}

// ---------------- weight prep: bf16 + transpose (once per call) ----------------

__global__ __launch_bounds__(256) void k_prep(const float* __restrict__ W1, const float* __restrict__ W2,
                                              unsigned short* __restrict__ w1t, unsigned short* __restrict__ w2t) {
  int idx = blockIdx.x * 256 + threadIdx.x;  // grid exact: 320*256 = 81920
  if (idx < 40960) {
    int l = idx >> 13, rem = idx & 8191;
    int n = rem >> 7, k = rem & 127;
    w1t[idx] = f2bf(W1[l * 8192 + k * 64 + n]);
  } else {
    int j = idx - 40960;
    int l = j >> 13, rem = j & 8191;
    int n = rem >> 6, k = rem & 63;
    w2t[j] = f2bf(W2[l * 8192 + k * 128 + n]);
  }
}

// ---------------- fused apply(prev layer) + MLP(this layer) ----------------
// mode 0: h_in = x (no norm apply).  mode 1: h = relu(norm(g)).  mode 2: h = relu(norm(g)) + h_old.
// Writes h (modes 1,2) and m = relu(h@W1+b1)@W2+b2 as bf16.
// var = E[(h-a*mean)^2] = E[h^2] - mean^2*(2a-a^2)

#define PADK 136  // 128+8 shorts: +16B row pad breaks LDS bank conflicts
#define PADH 72   // 64+8

__global__ __launch_bounds__(256) void k_mlpA(const float* __restrict__ xin, const float* __restrict__ gin,
                                              float* __restrict__ h, unsigned short* __restrict__ mout,
                                              const unsigned short* __restrict__ w1t,
                                              const unsigned short* __restrict__ w2t,
                                              const float* __restrict__ b1, const float* __restrict__ b2,
                                              const int* __restrict__ batch,
                                              const float* __restrict__ s1, const float* __restrict__ s2,
                                              const float* __restrict__ cntf,
                                              const float* __restrict__ gw, const float* __restrict__ gb,
                                              const float* __restrict__ ga, int mode) {
  __shared__ __align__(16) short hS[64 * PADK];   // h bf16; reused as m-out after phase 1
  __shared__ __align__(16) short w1S[64 * PADK];  // W1^T [n][k]
  __shared__ __align__(16) short hidS[64 * PADH]; // hidden [m][k]
  __shared__ __align__(16) short w2S[128 * PADH]; // W2^T [n][k]
  __shared__ float b1S[64];
  __shared__ float b2S[128];
  int t = threadIdx.x;
  int r0 = blockIdx.x * 64;  // grid 313: last block covers 32 valid rows
  // stage h into LDS bf16; for modes 1/2 compute GraphNorm apply on the fly and write new h
#pragma unroll
  for (int i = 0; i < 8; i++) {
    int idx = t + i * 256;  // float4 id, 2048 total
    int row = idx >> 5, c4 = idx & 31;
    int grow = r0 + row;
    float4 v = make_float4(0.f, 0.f, 0.f, 0.f);
    if (grow < N_NODES) {
      if (mode == 0) {
        v = ((const float4*)xin)[(size_t)grow * 32 + c4];
      } else {
        int gg = batch[grow];
        float invc = 1.0f / cntf[gg];
        float4 sm = ((const float4*)s1)[gg * 32 + c4];
        float4 se = ((const float4*)s2)[gg * 32 + c4];
        float4 av = ((const float4*)ga)[c4];
        float4 wv = ((const float4*)gw)[c4];
        float4 bv = ((const float4*)gb)[c4];
        float4 gv = ((const float4*)gin)[(size_t)grow * 32 + c4];
        float4 hv = make_float4(0.f, 0.f, 0.f, 0.f);
        if (mode == 2) hv = ((const float4*)h)[(size_t)grow * 32 + c4];
#define APPLY1(X)                                                         \
        {                                                                 \
          float mean = sm.X * invc;                                       \
          float ex2 = se.X * invc;                                        \
          float ac = av.X;                                                \
          float var = fmaxf(ex2 - mean * mean * (2.0f * ac - ac * ac), 0.0f); \
          float d = gv.X - ac * mean;                                     \
          float y = wv.X * (d * rsqrtf(var + EPS)) + bv.X;                \
          y = fmaxf(y, 0.0f);                                             \
          v.X = y + hv.X;                                                 \
        }
        APPLY1(x) APPLY1(y) APPLY1(z) APPLY1(w)
#undef APPLY1
        ((float4*)h)[(size_t)grow * 32 + c4] = v;
      }
    }
    ushort4 s;
    s.x = f2bf(v.x); s.y = f2bf(v.y); s.z = f2bf(v.z); s.w = f2bf(v.w);
    *(ushort4*)&hS[row * PADK + c4 * 4] = s;
  }
  // stage W1t (64x128 shorts = 1024 16B chunks) and W2t (128x64)
#pragma unroll
  for (int i = 0; i < 4; i++) {
    int idx = t + i * 256;
    *(int4*)&w1S[(idx >> 4) * PADK + (idx & 15) * 8] = ((const int4*)w1t)[idx];
    *(int4*)&w2S[(idx >> 3) * PADH + (idx & 7) * 8] = ((const int4*)w2t)[idx];
  }
  if (t < 64) b1S[t] = b1[t];
  else if (t < 192) b2S[t - 64] = b2[t - 64];
  __syncthreads();

  int w = t >> 6, lane = t & 63, lm = lane & 15, quad = lane >> 4;
  int mrow = w * 16 + lm;          // A-operand row for this lane
  int orow = w * 16 + quad * 4;    // C/D base row for this lane

  // phase 1: hid[64][64] = relu(h @ W1 + b1)
  f32x4 zero = {0.f, 0.f, 0.f, 0.f};
  f32x4 acc[4] = {zero, zero, zero, zero};
#pragma unroll
  for (int k0 = 0; k0 < 128; k0 += 32) {
    short8 a = *(const short8*)&hS[mrow * PADK + k0 + quad * 8];
#pragma unroll
    for (int nt = 0; nt < 4; nt++) {
      short8 b = *(const short8*)&w1S[(nt * 16 + lm) * PADK + k0 + quad * 8];
      acc[nt] = __builtin_amdgcn_mfma_f32_16x16x32_bf16(a, b, acc[nt], 0, 0, 0);
    }
  }
#pragma unroll
  for (int nt = 0; nt < 4; nt++) {
    int col = nt * 16 + lm;
    float bb = b1S[col];
#pragma unroll
    for (int r = 0; r < 4; r++)
      hidS[(orow + r) * PADH + col] = (short)f2bf(fmaxf(acc[nt][r] + bb, 0.0f));
  }
  __syncthreads();  // hidS ready; hS no longer read -> reusable as m-out

  // phase 2: m[64][128] = hid @ W2 + b2
  f32x4 acc2[8] = {zero, zero, zero, zero, zero, zero, zero, zero};
#pragma unroll
  for (int k0 = 0; k0 < 64; k0 += 32) {
    short8 a = *(const short8*)&hidS[mrow * PADH + k0 + quad * 8];
#pragma unroll
    for (int nt = 0; nt < 8; nt++) {
      short8 b = *(const short8*)&w2S[(nt * 16 + lm) * PADH + k0 + quad * 8];
      acc2[nt] = __builtin_amdgcn_mfma_f32_16x16x32_bf16(a, b, acc2[nt], 0, 0, 0);
    }
  }
#pragma unroll
  for (int nt = 0; nt < 8; nt++) {
    int col = nt * 16 + lm;
    float bb = b2S[col];
#pragma unroll
    for (int r = 0; r < 4; r++)
      hS[(orow + r) * PADK + col] = (short)f2bf(acc2[nt][r] + bb);
  }
  __syncthreads();
  // coalesced bf16 store of m
#pragma unroll
  for (int i = 0; i < 4; i++) {
    int idx = t + i * 256;
    int row = idx >> 4, cc = idx & 15;
    if (r0 + row < N_NODES)
      ((int4*)mout)[(size_t)(r0 + row) * 16 + cc] = *(const int4*)&hS[row * PADK + cc * 8];
  }
}

// ---------------- fused scatter-add + segment stats ----------------
// g[n] = m[n] + sum m[src[e]]; also s1 += g, s2 += g^2 (block-local LDS, then 256 atomics/block).

__global__ __launch_bounds__(512) void k_scatterS(const unsigned short* __restrict__ mbf, float* __restrict__ g,
                                                  const int* __restrict__ rowptr, const int* __restrict__ srcs,
                                                  const int* __restrict__ batch,
                                                  float* __restrict__ s1g, float* __restrict__ s2g) {
  __shared__ float s1L[128];
  __shared__ float s2L[128];
  int t = threadIdx.x;
  if (t < 128) s1L[t] = 0.0f;
  else if (t < 256) s2L[t - 128] = 0.0f;
  __syncthreads();
  int node = blockIdx.x * 8 + (t >> 6);  // grid exact: 2500*8 = 20000
  int lane = t & 63;
  int quarter = lane >> 4;
  int q16 = lane & 15;
  int g0 = batch[blockIdx.x * 8];  // block-dominant graph (boundary waves fall back to global atomics)
  const float4* m4 = (const float4*)mbf;
  float acc[8];
  union BU { float4 f; unsigned short u[8]; };
  if (quarter == 0) {  // self loop
    BU U; U.f = m4[(size_t)node * 16 + q16];
#pragma unroll
    for (int j = 0; j < 8; j++) acc[j] = bf2f(U.u[j]);
  } else {
#pragma unroll
    for (int j = 0; j < 8; j++) acc[j] = 0.0f;
  }
  int e = rowptr[node], e1 = rowptr[node + 1];
  for (; e + 16 <= e1; e += 16) {
    int i0 = srcs[e + quarter];
    int i1 = srcs[e + 4 + quarter];
    int i2 = srcs[e + 8 + quarter];
    int i3 = srcs[e + 12 + quarter];
    BU U0, U1, U2, U3;
    U0.f = m4[(size_t)i0 * 16 + q16];
    U1.f = m4[(size_t)i1 * 16 + q16];
    U2.f = m4[(size_t)i2 * 16 + q16];
    U3.f = m4[(size_t)i3 * 16 + q16];
#pragma unroll
    for (int j = 0; j < 8; j++)
      acc[j] += (bf2f(U0.u[j]) + bf2f(U1.u[j])) + (bf2f(U2.u[j]) + bf2f(U3.u[j]));
  }
  for (; e + 4 <= e1; e += 4) {
    BU U0; U0.f = m4[(size_t)srcs[e + quarter] * 16 + q16];
#pragma unroll
    for (int j = 0; j < 8; j++) acc[j] += bf2f(U0.u[j]);
  }
  if (e + quarter < e1) {
    BU U0; U0.f = m4[(size_t)srcs[e + quarter] * 16 + q16];
#pragma unroll
    for (int j = 0; j < 8; j++) acc[j] += bf2f(U0.u[j]);
  }
#pragma unroll
  for (int j = 0; j < 8; j++) {
    acc[j] += __shfl_xor(acc[j], 16);
    acc[j] += __shfl_xor(acc[j], 32);
  }
  if (quarter == 0) {
    float4* g4 = (float4*)(g + (size_t)node * 128 + q16 * 8);
    g4[0] = make_float4(acc[0], acc[1], acc[2], acc[3]);
    g4[1] = make_float4(acc[4], acc[5], acc[6], acc[7]);
    int gg = batch[node];
    if (gg == g0) {
#pragma unroll
      for (int j = 0; j < 8; j++) {
        atomicAdd(&s1L[q16 * 8 + j], acc[j]);
        atomicAdd(&s2L[q16 * 8 + j], acc[j] * acc[j]);
      }
    } else {  // rare graph-boundary wave
#pragma unroll
      for (int j = 0; j < 8; j++) {
        atomicAdd(&s1g[gg * 128 + q16 * 8 + j], acc[j]);
        atomicAdd(&s2g[gg * 128 + q16 * 8 + j], acc[j] * acc[j]);
      }
    }
  }
  __syncthreads();
  if (t < 128) atomicAdd(&s1g[g0 * 128 + t], s1L[t]);
  else if (t < 256) atomicAdd(&s2g[g0 * 128 + (t - 128)], s2L[t - 128]);
}

// ---------------- tail: apply(last layer) + mean-pool accumulate (no h store) ----------------

__global__ __launch_bounds__(256) void k_applyPool(const float* __restrict__ gin, const float* __restrict__ h,
                                                   const int* __restrict__ batch,
                                                   const float* __restrict__ s1, const float* __restrict__ s2,
                                                   const float* __restrict__ cntf,
                                                   const float* __restrict__ gw, const float* __restrict__ gb,
                                                   const float* __restrict__ ga, float* __restrict__ pooled) {
  __shared__ float poolL[128];
  int t = threadIdx.x;
  if (t < 128) poolL[t] = 0.0f;
  __syncthreads();
  int idx = blockIdx.x * 256 + t;  // float4 id; grid exact: 2500*256 = 640,000
  int n = idx >> 5, c4 = idx & 31;
  int g0 = batch[blockIdx.x * 8];
  int gg = batch[n];
  float invc = 1.0f / cntf[gg];
  float4 sm = ((const float4*)s1)[gg * 32 + c4];
  float4 se = ((const float4*)s2)[gg * 32 + c4];
  float4 av = ((const float4*)ga)[c4];
  float4 wv = ((const float4*)gw)[c4];
  float4 bv = ((const float4*)gb)[c4];
  float4 gv = ((const float4*)gin)[idx];
  float4 hv = ((const float4*)h)[idx];
  float4 o;
#define APPLY1(X)                                                          \
  {                                                                        \
    float mean = sm.X * invc;                                              \
    float ex2 = se.X * invc;                                               \
    float ac = av.X;                                                       \
    float var = fmaxf(ex2 - mean * mean * (2.0f * ac - ac * ac), 0.0f);    \
    float d = gv.X - ac * mean;                                            \
    float y = wv.X * (d * rsqrtf(var + EPS)) + bv.X;                       \
    o.X = fmaxf(y, 0.0f) + hv.X;                                           \
  }
  APPLY1(x) APPLY1(y) APPLY1(z) APPLY1(w)
#undef APPLY1
  if (gg == g0) {
    atomicAdd(&poolL[c4 * 4 + 0], o.x);
    atomicAdd(&poolL[c4 * 4 + 1], o.y);
    atomicAdd(&poolL[c4 * 4 + 2], o.z);
    atomicAdd(&poolL[c4 * 4 + 3], o.w);
  } else {
    atomicAdd(&pooled[gg * 128 + c4 * 4 + 0], o.x);
    atomicAdd(&pooled[gg * 128 + c4 * 4 + 1], o.y);
    atomicAdd(&pooled[gg * 128 + c4 * 4 + 2], o.z);
    atomicAdd(&pooled[gg * 128 + c4 * 4 + 3], o.w);
  }
  __syncthreads();
  if (t < 128) atomicAdd(&pooled[g0 * 128 + t], poolL[t]);
}

// ---------------- final pooled @ lin_w + lin_b ----------------

__global__ __launch_bounds__(256) void k_final(const float* __restrict__ pooled, const float* __restrict__ cntf,
                                               const float* __restrict__ lw, const float* __restrict__ lb,
                                               float* __restrict__ out) {
  int lane = threadIdx.x & 63, wave = threadIdx.x >> 6;
  for (int gi = 0; gi < 4; gi++) {
    int gidx = wave * 4 + gi;
    float s = pooled[gidx * 128 + lane] * lw[lane] + pooled[gidx * 128 + 64 + lane] * lw[64 + lane];
    for (int o = 32; o >= 1; o >>= 1) s += __shfl_down(s, o);
    if (lane == 0) out[gidx] = s / cntf[gidx] + lb[0];
  }
}

// ---------------- host ----------------

extern "C" void kernel_launch(void* const* d_in, const int* in_sizes, int n_in,
                              void* d_out, int out_size, void* d_ws, size_t ws_size,
                              hipStream_t stream) {
  const float* x = (const float*)d_in[0];
  const int* ei = (const int*)d_in[1];
  const int* batch = (const int*)d_in[2];
  const float* W1 = (const float*)d_in[3];
  const float* b1 = (const float*)d_in[4];
  const float* W2 = (const float*)d_in[5];
  const float* b2 = (const float*)d_in[6];
  const float* gnw = (const float*)d_in[7];
  const float* gnb = (const float*)d_in[8];
  const float* gna = (const float*)d_in[9];
  const float* lw = (const float*)d_in[10];
  const float* lb = (const float*)d_in[11];
  float* out = (float*)d_out;

  const int* srcI = ei;
  const int* dstI = ei + N_EDGES;

  char* p = (char*)d_ws;
  float* hbuf = (float*)(p + 0);                           // 10,240,000 B
  unsigned short* mbuf = (unsigned short*)(p + 10240000);  // 5,120,000 B (bf16)
  float* gbuf = (float*)(p + 15360000);                    // 10,240,000 B
  int* src_sorted = (int*)(p + 25600000);                  // 1,280,000 B
  int* rowptr = (int*)(p + 26880000);                      // 80,128 B
  int* cursor = (int*)(p + 26960128);                      // 80,128 B
  int* deg = (int*)(p + 27040256);                         // 80,128 B
  float* cntf = (float*)(p + 27120384);                    // 128 B
  unsigned short* w1t = (unsigned short*)(p + 27120512);   // 81,920 B
  unsigned short* w2t = (unsigned short*)(p + 27202432);   // 81,920 B
  float* sbufs = (float*)(p + 27284352);                   // 5 layers x (s1[2048], s2[2048]) = 81,920 B
  float* pooled = (float*)(p + 27366272);                  // 8,192 B (contiguous after sbufs)

  // CSR build + weight prep (once per call; edges & weights are layer-invariant)
  hipMemsetAsync(deg, 0, N_NODES * sizeof(int), stream);
  k_deg<<<N_EDGES / 256, 256, 0, stream>>>(dstI, deg);
  k_scan<<<1, 1024, 0, stream>>>(deg, rowptr, cursor, batch, cntf, sbufs);  // also zeroes sbufs+pooled
  k_fill<<<N_EDGES / 256, 256, 0, stream>>>(srcI, dstI, cursor, src_sorted);
  k_prep<<<320, 256, 0, stream>>>(W1, W2, w1t, w2t);

  for (int i = 0; i < N_LAYERS; i++) {
    int pi = (i > 0) ? (i - 1) : 0;  // previous layer's norm params/stats
    int mode = (i == 0) ? 0 : (i == 1 ? 1 : 2);
    k_mlpA<<<(N_NODES + 63) / 64, 256, 0, stream>>>(
        x, gbuf, hbuf, mbuf, w1t + (size_t)i * 8192, w2t + (size_t)i * 8192,
        b1 + (size_t)i * 64, b2 + (size_t)i * 128,
        batch, sbufs + (size_t)pi * 4096, sbufs + (size_t)pi * 4096 + 2048, cntf,
        gnw + (size_t)pi * 128, gnb + (size_t)pi * 128, gna + (size_t)pi * 128, mode);
    k_scatterS<<<N_NODES / 8, 512, 0, stream>>>(mbuf, gbuf, rowptr, src_sorted, batch,
                                                sbufs + (size_t)i * 4096, sbufs + (size_t)i * 4096 + 2048);
  }

  k_applyPool<<<N_NODES * N_FEAT / 4 / 256, 256, 0, stream>>>(
      gbuf, hbuf, batch, sbufs + 4 * 4096, sbufs + 4 * 4096 + 2048, cntf,
      gnw + 4 * 128, gnb + 4 * 128, gna + 4 * 128, pooled);
  k_final<<<1, 256, 0, stream>>>(pooled, cntf, lw, lb, out);
}

// Round 6
// 349.386 us; speedup vs baseline: 1.2929x; 1.2929x over previous
//
#include <hip/hip_runtime.h>

#define N_NODES 20000
#define N_EDGES 320000
#define N_FEAT 128
#define MLP_HID 64
#define N_GRAPHS 16
#define N_LAYERS 5
#define EPS 1e-5f

typedef __attribute__((ext_vector_type(8))) short short8;   // 8 bf16 = 4 VGPRs (MFMA A/B frag)
typedef __attribute__((ext_vector_type(4))) float f32x4;    // MFMA C/D frag

__device__ inline float bf2f(unsigned short u) { return __uint_as_float(((unsigned)u) << 16); }
__device__ inline unsigned short f2bf(float f) {
  unsigned u = __float_as_uint(f);
  u += 0x7FFF + ((u >> 16) & 1);  // RNE
  return (unsigned short)(u >> 16);
}

// ---------------- CSR build ----------------

__global__ __launch_bounds__(256) void k_deg(const int* __restrict__ dst, int* __restrict__ deg) {
  int e = blockIdx.x * 256 + threadIdx.x;  // grid exact: 1250*256 = 320000
  atomicAdd(&deg[dst[e]], 1);
}

__global__ __launch_bounds__(1024) void k_scan(const int* __restrict__ deg, int* __restrict__ rowptr,
                                               int* __restrict__ cursor, const int* __restrict__ batch,
                                               float* __restrict__ cntf, float* __restrict__ zero_region) {
  __shared__ int sdata[1024];
  __shared__ int spos[17];
  constexpr int CH = 20;  // 1024*20 = 20480 >= 20000
  int t = threadIdx.x;
  // zero all per-layer stat buffers + pooled (contiguous: 22528 floats)
  for (int i = t; i < 22528; i += 1024) zero_region[i] = 0.0f;
  int base = t * CH;
  int loc[CH];
  int partial = 0;
#pragma unroll
  for (int i = 0; i < CH; i++) {
    int idx = base + i;
    int v = (idx < N_NODES) ? deg[idx] : 0;
    loc[i] = v;
    partial += v;
  }
  sdata[t] = partial;
  __syncthreads();
  for (int off = 1; off < 1024; off <<= 1) {
    int v = (t >= off) ? sdata[t - off] : 0;
    __syncthreads();
    sdata[t] += v;
    __syncthreads();
  }
  int run = sdata[t] - partial;  // exclusive prefix
#pragma unroll
  for (int i = 0; i < CH; i++) {
    int idx = base + i;
    if (idx < N_NODES) {
      rowptr[idx] = run;
      cursor[idx] = run;
      run += loc[i];
    }
  }
  if (t == 1023) rowptr[N_NODES] = sdata[1023];
  if (t < 17) {  // per-graph counts via binary search on sorted batch
    int lo = 0, hi = N_NODES;
    while (lo < hi) {
      int mid = (lo + hi) >> 1;
      if (batch[mid] < t) lo = mid + 1; else hi = mid;
    }
    spos[t] = lo;
  }
  __syncthreads();
  if (t < N_GRAPHS) cntf[t] = fmaxf((float)(spos[t + 1] - spos[t]), 1.0f);
}

__global__ __launch_bounds__(256) void k_fill(const int* __restrict__ src, const int* __restrict__ dst,
                                              int* __restrict__ cursor, int* __restrict__ src_sorted) {
  int e = blockIdx.x * 256 + threadIdx.x;  // grid exact
  int d = dst[e];
  int p = atomicAdd(&cursor[d], 1);
  src_sorted[p] = src[e];
}

// ---------------- weight prep: bf16 + transpose (once per call) ----------------

__global__ __launch_bounds__(256) void k_prep(const float* __restrict__ W1, const float* __restrict__ W2,
                                              unsigned short* __restrict__ w1t, unsigned short* __restrict__ w2t) {
  int idx = blockIdx.x * 256 + threadIdx.x;  // grid exact: 320*256 = 81920
  if (idx < 40960) {
    int l = idx >> 13, rem = idx & 8191;
    int n = rem >> 7, k = rem & 127;
    w1t[idx] = f2bf(W1[l * 8192 + k * 64 + n]);
  } else {
    int j = idx - 40960;
    int l = j >> 13, rem = j & 8191;
    int n = rem >> 6, k = rem & 63;
    w2t[j] = f2bf(W2[l * 8192 + k * 128 + n]);
  }
}

// ---------------- fused apply(prev layer) + MLP(this layer) ----------------
// mode 0: h_in = x (no norm apply).  mode 1: h = relu(norm(g)).  mode 2: h = relu(norm(g)) + h_old.
// Writes h (modes 1,2) and m = relu(h@W1+b1)@W2+b2 as bf16.
// var = E[(h-a*mean)^2] = E[h^2] - mean^2*(2a-a^2)

#define PADK 136  // 128+8 shorts: +16B row pad breaks LDS bank conflicts
#define PADH 72   // 64+8

__global__ __launch_bounds__(256) void k_mlpA(const float* __restrict__ xin, const float* __restrict__ gin,
                                              float* __restrict__ h, unsigned short* __restrict__ mout,
                                              const unsigned short* __restrict__ w1t,
                                              const unsigned short* __restrict__ w2t,
                                              const float* __restrict__ b1, const float* __restrict__ b2,
                                              const int* __restrict__ batch,
                                              const float* __restrict__ s1, const float* __restrict__ s2,
                                              const float* __restrict__ cntf,
                                              const float* __restrict__ gw, const float* __restrict__ gb,
                                              const float* __restrict__ ga, int mode) {
  __shared__ __align__(16) short hS[64 * PADK];   // h bf16; reused as m-out after phase 1
  __shared__ __align__(16) short w1S[64 * PADK];  // W1^T [n][k]
  __shared__ __align__(16) short hidS[64 * PADH]; // hidden [m][k]
  __shared__ __align__(16) short w2S[128 * PADH]; // W2^T [n][k]
  __shared__ float b1S[64];
  __shared__ float b2S[128];
  int t = threadIdx.x;
  int r0 = blockIdx.x * 64;  // grid 313: last block covers 32 valid rows
  // stage h into LDS bf16; for modes 1/2 compute GraphNorm apply on the fly and write new h
#pragma unroll
  for (int i = 0; i < 8; i++) {
    int idx = t + i * 256;  // float4 id, 2048 total
    int row = idx >> 5, c4 = idx & 31;
    int grow = r0 + row;
    float4 v = make_float4(0.f, 0.f, 0.f, 0.f);
    if (grow < N_NODES) {
      if (mode == 0) {
        v = ((const float4*)xin)[(size_t)grow * 32 + c4];
      } else {
        int gg = batch[grow];
        float invc = 1.0f / cntf[gg];
        float4 sm = ((const float4*)s1)[gg * 32 + c4];
        float4 se = ((const float4*)s2)[gg * 32 + c4];
        float4 av = ((const float4*)ga)[c4];
        float4 wv = ((const float4*)gw)[c4];
        float4 bv = ((const float4*)gb)[c4];
        float4 gv = ((const float4*)gin)[(size_t)grow * 32 + c4];
        float4 hv = make_float4(0.f, 0.f, 0.f, 0.f);
        if (mode == 2) hv = ((const float4*)h)[(size_t)grow * 32 + c4];
#define APPLY1(X)                                                         \
        {                                                                 \
          float mean = sm.X * invc;                                       \
          float ex2 = se.X * invc;                                        \
          float ac = av.X;                                                \
          float var = fmaxf(ex2 - mean * mean * (2.0f * ac - ac * ac), 0.0f); \
          float d = gv.X - ac * mean;                                     \
          float y = wv.X * (d * rsqrtf(var + EPS)) + bv.X;                \
          y = fmaxf(y, 0.0f);                                             \
          v.X = y + hv.X;                                                 \
        }
        APPLY1(x) APPLY1(y) APPLY1(z) APPLY1(w)
#undef APPLY1
        ((float4*)h)[(size_t)grow * 32 + c4] = v;
      }
    }
    ushort4 s;
    s.x = f2bf(v.x); s.y = f2bf(v.y); s.z = f2bf(v.z); s.w = f2bf(v.w);
    *(ushort4*)&hS[row * PADK + c4 * 4] = s;
  }
  // stage W1t (64x128 shorts = 1024 16B chunks) and W2t (128x64)
#pragma unroll
  for (int i = 0; i < 4; i++) {
    int idx = t + i * 256;
    *(int4*)&w1S[(idx >> 4) * PADK + (idx & 15) * 8] = ((const int4*)w1t)[idx];
    *(int4*)&w2S[(idx >> 3) * PADH + (idx & 7) * 8] = ((const int4*)w2t)[idx];
  }
  if (t < 64) b1S[t] = b1[t];
  else if (t < 192) b2S[t - 64] = b2[t - 64];
  __syncthreads();

  int w = t >> 6, lane = t & 63, lm = lane & 15, quad = lane >> 4;
  int mrow = w * 16 + lm;          // A-operand row for this lane
  int orow = w * 16 + quad * 4;    // C/D base row for this lane

  // phase 1: hid[64][64] = relu(h @ W1 + b1)
  f32x4 zero = {0.f, 0.f, 0.f, 0.f};
  f32x4 acc[4] = {zero, zero, zero, zero};
#pragma unroll
  for (int k0 = 0; k0 < 128; k0 += 32) {
    short8 a = *(const short8*)&hS[mrow * PADK + k0 + quad * 8];
#pragma unroll
    for (int nt = 0; nt < 4; nt++) {
      short8 b = *(const short8*)&w1S[(nt * 16 + lm) * PADK + k0 + quad * 8];
      acc[nt] = __builtin_amdgcn_mfma_f32_16x16x32_bf16(a, b, acc[nt], 0, 0, 0);
    }
  }
#pragma unroll
  for (int nt = 0; nt < 4; nt++) {
    int col = nt * 16 + lm;
    float bb = b1S[col];
#pragma unroll
    for (int r = 0; r < 4; r++)
      hidS[(orow + r) * PADH + col] = (short)f2bf(fmaxf(acc[nt][r] + bb, 0.0f));
  }
  __syncthreads();  // hidS ready; hS no longer read -> reusable as m-out

  // phase 2: m[64][128] = hid @ W2 + b2
  f32x4 acc2[8] = {zero, zero, zero, zero, zero, zero, zero, zero};
#pragma unroll
  for (int k0 = 0; k0 < 64; k0 += 32) {
    short8 a = *(const short8*)&hidS[mrow * PADH + k0 + quad * 8];
#pragma unroll
    for (int nt = 0; nt < 8; nt++) {
      short8 b = *(const short8*)&w2S[(nt * 16 + lm) * PADH + k0 + quad * 8];
      acc2[nt] = __builtin_amdgcn_mfma_f32_16x16x32_bf16(a, b, acc2[nt], 0, 0, 0);
    }
  }
#pragma unroll
  for (int nt = 0; nt < 8; nt++) {
    int col = nt * 16 + lm;
    float bb = b2S[col];
#pragma unroll
    for (int r = 0; r < 4; r++)
      hS[(orow + r) * PADK + col] = (short)f2bf(acc2[nt][r] + bb);
  }
  __syncthreads();
  // coalesced bf16 store of m
#pragma unroll
  for (int i = 0; i < 4; i++) {
    int idx = t + i * 256;
    int row = idx >> 4, cc = idx & 15;
    if (r0 + row < N_NODES)
      ((int4*)mout)[(size_t)(r0 + row) * 16 + cc] = *(const int4*)&hS[row * PADK + cc * 8];
  }
}

// ---------------- scatter-add: g[n] = m[n] + sum m[src[e]], m is bf16 ----------------
// One free-running wave per node, NO block-level syncs (round-5 lesson: coupling
// a latency-bound gather behind __syncthreads + atomic flush cost 4x).

__global__ __launch_bounds__(256) void k_scatter(const unsigned short* __restrict__ mbf, float* __restrict__ g,
                                                 const int* __restrict__ rowptr, const int* __restrict__ srcs) {
  int node = (blockIdx.x * 256 + threadIdx.x) >> 6;  // grid exact: 5000*4 waves
  int lane = threadIdx.x & 63;
  int quarter = lane >> 4;
  int q16 = lane & 15;
  const float4* m4 = (const float4*)mbf;
  float acc[8];
  union BU { float4 f; unsigned short u[8]; };
  if (quarter == 0) {  // self loop
    BU U; U.f = m4[(size_t)node * 16 + q16];
#pragma unroll
    for (int j = 0; j < 8; j++) acc[j] = bf2f(U.u[j]);
  } else {
#pragma unroll
    for (int j = 0; j < 8; j++) acc[j] = 0.0f;
  }
  int e = rowptr[node], e1 = rowptr[node + 1];
  for (; e + 16 <= e1; e += 16) {
    int i0 = srcs[e + quarter];
    int i1 = srcs[e + 4 + quarter];
    int i2 = srcs[e + 8 + quarter];
    int i3 = srcs[e + 12 + quarter];
    BU U0, U1, U2, U3;
    U0.f = m4[(size_t)i0 * 16 + q16];
    U1.f = m4[(size_t)i1 * 16 + q16];
    U2.f = m4[(size_t)i2 * 16 + q16];
    U3.f = m4[(size_t)i3 * 16 + q16];
#pragma unroll
    for (int j = 0; j < 8; j++)
      acc[j] += (bf2f(U0.u[j]) + bf2f(U1.u[j])) + (bf2f(U2.u[j]) + bf2f(U3.u[j]));
  }
  for (; e + 4 <= e1; e += 4) {
    BU U0; U0.f = m4[(size_t)srcs[e + quarter] * 16 + q16];
#pragma unroll
    for (int j = 0; j < 8; j++) acc[j] += bf2f(U0.u[j]);
  }
  if (e + quarter < e1) {
    BU U0; U0.f = m4[(size_t)srcs[e + quarter] * 16 + q16];
#pragma unroll
    for (int j = 0; j < 8; j++) acc[j] += bf2f(U0.u[j]);
  }
#pragma unroll
  for (int j = 0; j < 8; j++) {
    acc[j] += __shfl_xor(acc[j], 16);
    acc[j] += __shfl_xor(acc[j], 32);
  }
  if (quarter == 0) {
    float4* g4 = (float4*)(g + (size_t)node * 128 + q16 * 8);
    g4[0] = make_float4(acc[0], acc[1], acc[2], acc[3]);
    g4[1] = make_float4(acc[4], acc[5], acc[6], acc[7]);
  }
}

// ---------------- one-pass segment stats: s1 = sum(g), s2 = sum(g^2) ----------------

#define STAT_CHUNK 8  // 2500 blocks * 8 = 20000 exact

__global__ __launch_bounds__(128) void k_stats(const float* __restrict__ in, const int* __restrict__ batch,
                                               float* __restrict__ s1, float* __restrict__ s2) {
  int n0 = blockIdx.x * STAT_CHUNK;
  int c = threadIdx.x;
  int curg = batch[n0];
  float a1 = 0.0f, a2 = 0.0f;
#pragma unroll
  for (int k = 0; k < STAT_CHUNK; k++) {
    int n = n0 + k;
    int gg = batch[n];
    if (gg != curg) {  // block-uniform branch (batch sorted)
      atomicAdd(&s1[curg * 128 + c], a1);
      atomicAdd(&s2[curg * 128 + c], a2);
      a1 = 0.0f; a2 = 0.0f;
      curg = gg;
    }
    float v = in[(size_t)n * 128 + c];
    a1 += v;
    a2 += v * v;
  }
  atomicAdd(&s1[curg * 128 + c], a1);
  atomicAdd(&s2[curg * 128 + c], a2);
}

// ---------------- tail: apply(last layer) + mean-pool accumulate (no h store) ----------------

__global__ __launch_bounds__(256) void k_applyPool(const float* __restrict__ gin, const float* __restrict__ h,
                                                   const int* __restrict__ batch,
                                                   const float* __restrict__ s1, const float* __restrict__ s2,
                                                   const float* __restrict__ cntf,
                                                   const float* __restrict__ gw, const float* __restrict__ gb,
                                                   const float* __restrict__ ga, float* __restrict__ pooled) {
  __shared__ float poolL[128];
  int t = threadIdx.x;
  if (t < 128) poolL[t] = 0.0f;
  __syncthreads();
  int idx = blockIdx.x * 256 + t;  // float4 id; grid exact: 2500*256 = 640,000
  int n = idx >> 5, c4 = idx & 31;
  int g0 = batch[blockIdx.x * 8];
  int gg = batch[n];
  float invc = 1.0f / cntf[gg];
  float4 sm = ((const float4*)s1)[gg * 32 + c4];
  float4 se = ((const float4*)s2)[gg * 32 + c4];
  float4 av = ((const float4*)ga)[c4];
  float4 wv = ((const float4*)gw)[c4];
  float4 bv = ((const float4*)gb)[c4];
  float4 gv = ((const float4*)gin)[idx];
  float4 hv = ((const float4*)h)[idx];
  float4 o;
#define APPLY1(X)                                                          \
  {                                                                        \
    float mean = sm.X * invc;                                              \
    float ex2 = se.X * invc;                                               \
    float ac = av.X;                                                       \
    float var = fmaxf(ex2 - mean * mean * (2.0f * ac - ac * ac), 0.0f);    \
    float d = gv.X - ac * mean;                                            \
    float y = wv.X * (d * rsqrtf(var + EPS)) + bv.X;                       \
    o.X = fmaxf(y, 0.0f) + hv.X;                                           \
  }
  APPLY1(x) APPLY1(y) APPLY1(z) APPLY1(w)
#undef APPLY1
  if (gg == g0) {
    atomicAdd(&poolL[c4 * 4 + 0], o.x);
    atomicAdd(&poolL[c4 * 4 + 1], o.y);
    atomicAdd(&poolL[c4 * 4 + 2], o.z);
    atomicAdd(&poolL[c4 * 4 + 3], o.w);
  } else {
    atomicAdd(&pooled[gg * 128 + c4 * 4 + 0], o.x);
    atomicAdd(&pooled[gg * 128 + c4 * 4 + 1], o.y);
    atomicAdd(&pooled[gg * 128 + c4 * 4 + 2], o.z);
    atomicAdd(&pooled[gg * 128 + c4 * 4 + 3], o.w);
  }
  __syncthreads();
  if (t < 128) atomicAdd(&pooled[g0 * 128 + t], poolL[t]);
}

// ---------------- final pooled @ lin_w + lin_b ----------------

__global__ __launch_bounds__(256) void k_final(const float* __restrict__ pooled, const float* __restrict__ cntf,
                                               const float* __restrict__ lw, const float* __restrict__ lb,
                                               float* __restrict__ out) {
  int lane = threadIdx.x & 63, wave = threadIdx.x >> 6;
  for (int gi = 0; gi < 4; gi++) {
    int gidx = wave * 4 + gi;
    float s = pooled[gidx * 128 + lane] * lw[lane] + pooled[gidx * 128 + 64 + lane] * lw[64 + lane];
    for (int o = 32; o >= 1; o >>= 1) s += __shfl_down(s, o);
    if (lane == 0) out[gidx] = s / cntf[gidx] + lb[0];
  }
}

// ---------------- host ----------------

extern "C" void kernel_launch(void* const* d_in, const int* in_sizes, int n_in,
                              void* d_out, int out_size, void* d_ws, size_t ws_size,
                              hipStream_t stream) {
  const float* x = (const float*)d_in[0];
  const int* ei = (const int*)d_in[1];
  const int* batch = (const int*)d_in[2];
  const float* W1 = (const float*)d_in[3];
  const float* b1 = (const float*)d_in[4];
  const float* W2 = (const float*)d_in[5];
  const float* b2 = (const float*)d_in[6];
  const float* gnw = (const float*)d_in[7];
  const float* gnb = (const float*)d_in[8];
  const float* gna = (const float*)d_in[9];
  const float* lw = (const float*)d_in[10];
  const float* lb = (const float*)d_in[11];
  float* out = (float*)d_out;

  const int* srcI = ei;
  const int* dstI = ei + N_EDGES;

  char* p = (char*)d_ws;
  float* hbuf = (float*)(p + 0);                           // 10,240,000 B
  unsigned short* mbuf = (unsigned short*)(p + 10240000);  // 5,120,000 B (bf16)
  float* gbuf = (float*)(p + 15360000);                    // 10,240,000 B
  int* src_sorted = (int*)(p + 25600000);                  // 1,280,000 B
  int* rowptr = (int*)(p + 26880000);                      // 80,128 B
  int* cursor = (int*)(p + 26960128);                      // 80,128 B
  int* deg = (int*)(p + 27040256);                         // 80,128 B
  float* cntf = (float*)(p + 27120384);                    // 128 B
  unsigned short* w1t = (unsigned short*)(p + 27120512);   // 81,920 B
  unsigned short* w2t = (unsigned short*)(p + 27202432);   // 81,920 B
  float* sbufs = (float*)(p + 27284352);                   // 5 layers x (s1[2048], s2[2048]) = 81,920 B
  float* pooled = (float*)(p + 27366272);                  // 8,192 B (contiguous after sbufs)

  // CSR build + weight prep (once per call; edges & weights are layer-invariant)
  hipMemsetAsync(deg, 0, N_NODES * sizeof(int), stream);
  k_deg<<<N_EDGES / 256, 256, 0, stream>>>(dstI, deg);
  k_scan<<<1, 1024, 0, stream>>>(deg, rowptr, cursor, batch, cntf, sbufs);  // also zeroes sbufs+pooled
  k_fill<<<N_EDGES / 256, 256, 0, stream>>>(srcI, dstI, cursor, src_sorted);
  k_prep<<<320, 256, 0, stream>>>(W1, W2, w1t, w2t);

  for (int i = 0; i < N_LAYERS; i++) {
    int pi = (i > 0) ? (i - 1) : 0;  // previous layer's norm params/stats
    int mode = (i == 0) ? 0 : (i == 1 ? 1 : 2);
    k_mlpA<<<(N_NODES + 63) / 64, 256, 0, stream>>>(
        x, gbuf, hbuf, mbuf, w1t + (size_t)i * 8192, w2t + (size_t)i * 8192,
        b1 + (size_t)i * 64, b2 + (size_t)i * 128,
        batch, sbufs + (size_t)pi * 4096, sbufs + (size_t)pi * 4096 + 2048, cntf,
        gnw + (size_t)pi * 128, gnb + (size_t)pi * 128, gna + (size_t)pi * 128, mode);
    k_scatter<<<N_NODES / 4, 256, 0, stream>>>(mbuf, gbuf, rowptr, src_sorted);
    k_stats<<<N_NODES / STAT_CHUNK, 128, 0, stream>>>(gbuf, batch,
                                                      sbufs + (size_t)i * 4096, sbufs + (size_t)i * 4096 + 2048);
  }

  k_applyPool<<<N_NODES * N_FEAT / 4 / 256, 256, 0, stream>>>(
      gbuf, hbuf, batch, sbufs + 4 * 4096, sbufs + 4 * 4096 + 2048, cntf,
      gnw + 4 * 128, gnb + 4 * 128, gna + 4 * 128, pooled);
  k_final<<<1, 256, 0, stream>>>(pooled, cntf, lw, lb, out);
}